// Round 1
// baseline (332.542 us; speedup 1.0000x reference)
//
#include <hip/hip_runtime.h>
#include <hip/hip_bf16.h>

typedef __bf16 bf16x8 __attribute__((ext_vector_type(8)));
typedef float  f32x4  __attribute__((ext_vector_type(4)));

// ---------------------------------------------------------------------------
// Kernel 1: prep
//  blocks [0,4096):    U,V  — per-object GEMM vs g_w1 rows [0:66) and [66:132)
//  blocks [4096,4160): Qb   — ques @ g_w1[132:388) + g_b1
//  blocks [4160,4928): bf16 transpose of g_w2/g_w3/g_w4 -> W^T (256 out x 256 in)
// ---------------------------------------------------------------------------
__global__ __launch_bounds__(256) void prep_kernel(
    const float* __restrict__ img, const float* __restrict__ ques,
    const float* __restrict__ g_w1, const float* __restrict__ g_b1,
    const float* __restrict__ g_w2, const float* __restrict__ g_w3,
    const float* __restrict__ g_w4,
    float* __restrict__ U, float* __restrict__ V, float* __restrict__ Qb,
    __bf16* __restrict__ W2t, __bf16* __restrict__ W3t, __bf16* __restrict__ W4t) {
  __shared__ float sbuf[256];
  const int blk = blockIdx.x;
  const int t = threadIdx.x;

  if (blk < 4096) {
    const int n = blk >> 6, o = blk & 63;
    if (t < 66) {
      float v;
      if (t < 64)      v = img[(n * 64 + t) * 64 + o];   // img[n][c][o]
      else if (t == 64) v = (float)(o >> 3);             // idx // 8
      else              v = (float)(o & 7);              // idx % 8
      sbuf[t] = v;
    }
    __syncthreads();
    float u = 0.f, vv = 0.f;
#pragma unroll
    for (int d = 0; d < 66; ++d) {
      const float c = sbuf[d];
      u  += c * g_w1[d * 256 + t];
      vv += c * g_w1[(66 + d) * 256 + t];
    }
    U[blk * 256 + t] = u;
    V[blk * 256 + t] = vv;
  } else if (blk < 4160) {
    const int n = blk - 4096;
    sbuf[t] = ques[n * 256 + t];
    __syncthreads();
    float s = g_b1[t];
    for (int e = 0; e < 256; ++e) s += sbuf[e] * g_w1[(132 + e) * 256 + t];
    Qb[n * 256 + t] = s;
  } else {
    const int b2 = blk - 4160;            // 0..767
    const int wsel = b2 >> 8;             // which weight
    const int nrow = b2 & 255;            // output-channel row of W^T
    const float* W = (wsel == 0) ? g_w2 : (wsel == 1) ? g_w3 : g_w4;
    __bf16* Wt    = (wsel == 0) ? W2t  : (wsel == 1) ? W3t  : W4t;
    Wt[nrow * 256 + t] = (__bf16)W[t * 256 + nrow];
  }
}

// ---------------------------------------------------------------------------
// Kernel 2: fused g-MLP layers 2..4 with MFMA, one block per (image, object i)
//  64 rows (all j), 256 cols; H in LDS (bf16, row pitch 264 to break bank alias)
// ---------------------------------------------------------------------------
#define HP 264   // padded row pitch (bf16 elems); 264*2 = 528 B = 33*16 B

template <bool LAST>
__device__ __forceinline__ void g_layer(__bf16* Hs, const __bf16* __restrict__ Wt,
                                        const float* __restrict__ bias_g,
                                        int w, int q, int r16,
                                        float* __restrict__ part_row) {
  f32x4 acc[4][4];
  const f32x4 z = {0.f, 0.f, 0.f, 0.f};
#pragma unroll
  for (int m = 0; m < 4; ++m)
#pragma unroll
    for (int n = 0; n < 4; ++n) acc[m][n] = z;

  for (int ks = 0; ks < 8; ++ks) {
    const int kof = ks * 32 + q * 8;
    bf16x8 a[4], b[4];
#pragma unroll
    for (int m = 0; m < 4; ++m)
      a[m] = *(const bf16x8*)(&Hs[(m * 16 + r16) * HP + kof]);
#pragma unroll
    for (int n = 0; n < 4; ++n)
      b[n] = *(const bf16x8*)(&Wt[(size_t)(w * 64 + n * 16 + r16) * 256 + kof]);
#pragma unroll
    for (int m = 0; m < 4; ++m)
#pragma unroll
      for (int n = 0; n < 4; ++n)
        acc[m][n] = __builtin_amdgcn_mfma_f32_16x16x32_bf16(a[m], b[n], acc[m][n], 0, 0, 0);
  }

  float bias[4];
#pragma unroll
  for (int n = 0; n < 4; ++n) bias[n] = bias_g[w * 64 + n * 16 + r16];

  __syncthreads();   // all waves finished reading Hs

  if (!LAST) {
#pragma unroll
    for (int m = 0; m < 4; ++m)
#pragma unroll
      for (int n = 0; n < 4; ++n) {
        const int col = w * 64 + n * 16 + r16;
#pragma unroll
        for (int r = 0; r < 4; ++r) {
          const int row = m * 16 + q * 4 + r;
          const float v = fmaxf(acc[m][n][r] + bias[n], 0.f);
          Hs[row * HP + col] = (__bf16)v;
        }
      }
    __syncthreads();
  } else {
    // sum relu(acc+bias) over all 64 rows -> one partial per column
#pragma unroll
    for (int n = 0; n < 4; ++n) {
      float s = 0.f;
#pragma unroll
      for (int m = 0; m < 4; ++m)
#pragma unroll
        for (int r = 0; r < 4; ++r)
          s += fmaxf(acc[m][n][r] + bias[n], 0.f);
      s += __shfl_xor(s, 16, 64);
      s += __shfl_xor(s, 32, 64);
      if (q == 0) part_row[w * 64 + n * 16 + r16] = s;
    }
  }
}

__global__ __launch_bounds__(256) void rn_main(
    const float* __restrict__ U, const float* __restrict__ V,
    const float* __restrict__ Qb,
    const __bf16* __restrict__ W2t, const __bf16* __restrict__ W3t,
    const __bf16* __restrict__ W4t,
    const float* __restrict__ b2, const float* __restrict__ b3,
    const float* __restrict__ b4,
    float* __restrict__ part) {
  __shared__ __bf16 Hs[64 * HP];
  const int blk = blockIdx.x;
  const int nimg = blk >> 6, iobj = blk & 63;
  const int t = threadIdx.x;

  // phase 0: h1[j][t] = relu(U[n,i,t] + V[n,j,t] + Qb[n,t]) -> bf16 LDS
  {
    const float u = U[(nimg * 64 + iobj) * 256 + t] + Qb[nimg * 256 + t];
    const float* Vp = V + (size_t)nimg * 64 * 256 + t;
#pragma unroll 4
    for (int j = 0; j < 64; ++j) {
      const float hv = fmaxf(u + Vp[j * 256], 0.f);
      Hs[j * HP + t] = (__bf16)hv;
    }
  }
  __syncthreads();

  const int w = t >> 6, L = t & 63;
  const int q = L >> 4, r16 = L & 15;
  float* part_row = part + (size_t)blk * 256;

  g_layer<false>(Hs, W2t, b2, w, q, r16, part_row);
  g_layer<false>(Hs, W3t, b3, w, q, r16, part_row);
  g_layer<true >(Hs, W4t, b4, w, q, r16, part_row);
}

// ---------------------------------------------------------------------------
// Kernel 3: reduce partials -> context, f-MLP (fp32), log_softmax
// ---------------------------------------------------------------------------
__global__ __launch_bounds__(256) void rn_final(
    const float* __restrict__ part,
    const float* __restrict__ f_w1, const float* __restrict__ f_b1,
    const float* __restrict__ f_w2, const float* __restrict__ f_b2,
    const float* __restrict__ f_w3, const float* __restrict__ f_b3,
    float* __restrict__ out) {
  __shared__ float ctx[256], y1[256], y2[256], sc[2];
  const int n = blockIdx.x, t = threadIdx.x;

  float s = 0.f;
  for (int i = 0; i < 64; ++i) s += part[((size_t)n * 64 + i) * 256 + t];
  ctx[t] = s * (1.0f / 4096.0f);
  __syncthreads();

  float a = f_b1[t];
  for (int k = 0; k < 256; ++k) a += ctx[k] * f_w1[k * 256 + t];
  y1[t] = fmaxf(a, 0.f);
  __syncthreads();

  float b = f_b2[t];
  for (int k = 0; k < 256; ++k) b += y1[k] * f_w2[k * 256 + t];
  y2[t] = fmaxf(b, 0.f);
  __syncthreads();

  if (t < 2) {
    float c = f_b3[t];
    for (int k = 0; k < 256; ++k) c += y2[k] * f_w3[k * 2 + t];
    sc[t] = c;
  }
  __syncthreads();

  if (t == 0) {
    const float s0 = sc[0], s1 = sc[1];
    const float mx = fmaxf(s0, s1);
    const float lse = mx + logf(expf(s0 - mx) + expf(s1 - mx));
    out[n * 2 + 0] = s0 - lse;
    out[n * 2 + 1] = s1 - lse;
  }
}

// ---------------------------------------------------------------------------
extern "C" void kernel_launch(void* const* d_in, const int* in_sizes, int n_in,
                              void* d_out, int out_size, void* d_ws, size_t ws_size,
                              hipStream_t stream) {
  const float* img  = (const float*)d_in[0];
  const float* ques = (const float*)d_in[1];
  const float* g_w1 = (const float*)d_in[2];
  const float* g_b1 = (const float*)d_in[3];
  const float* g_w2 = (const float*)d_in[4];
  const float* g_b2 = (const float*)d_in[5];
  const float* g_w3 = (const float*)d_in[6];
  const float* g_b3 = (const float*)d_in[7];
  const float* g_w4 = (const float*)d_in[8];
  const float* g_b4 = (const float*)d_in[9];
  const float* f_w1 = (const float*)d_in[10];
  const float* f_b1 = (const float*)d_in[11];
  const float* f_w2 = (const float*)d_in[12];
  const float* f_b2 = (const float*)d_in[13];
  const float* f_w3 = (const float*)d_in[14];
  const float* f_b3 = (const float*)d_in[15];
  float* out = (float*)d_out;

  char* ws = (char*)d_ws;
  float*  U    = (float*)(ws);                                 // 4096*256 f32 = 4 MB
  float*  V    = (float*)(ws + (size_t)4  * 1048576);          // 4 MB
  float*  part = (float*)(ws + (size_t)8  * 1048576);          // 4 MB
  float*  Qb   = (float*)(ws + (size_t)12 * 1048576);          // 64 KB
  __bf16* W2t  = (__bf16*)(ws + (size_t)12 * 1048576 + 65536); // 128 KB each
  __bf16* W3t  = W2t + 65536;
  __bf16* W4t  = W3t + 65536;

  prep_kernel<<<4928, 256, 0, stream>>>(img, ques, g_w1, g_b1, g_w2, g_w3, g_w4,
                                        U, V, Qb, W2t, W3t, W4t);
  rn_main<<<4096, 256, 0, stream>>>(U, V, Qb, W2t, W3t, W4t, g_b2, g_b3, g_b4, part);
  rn_final<<<64, 256, 0, stream>>>(part, f_w1, f_b1, f_w2, f_b2, f_w3, f_b3, out);
}